// Round 19
// baseline (65.500 us; speedup 1.0000x reference)
//
#include <hip/hip_runtime.h>

#define LN2 0.6931471805599453f

typedef float f32x4 __attribute__((ext_vector_type(4)));

// lane i <- lane i-1 (value), lane 0 <- 0.0f   (wave_shr:1)
__device__ __forceinline__ float dpp_shr1_zero(float x) {
    return __int_as_float(__builtin_amdgcn_update_dpp(
        0, __float_as_int(x), 0x138, 0xF, 0xF, true));
}
// lane i <- lane i-1 (int), lane 0 keeps own
__device__ __forceinline__ int dpp_shr1_keep(int x) {
    return __builtin_amdgcn_update_dpp(x, x, 0x138, 0xF, 0xF, false);
}
// lane i <- lane i+1 (value), lane 63 <- 0.0f  (wave_shl:1)
__device__ __forceinline__ float dpp_shl1_zero(float x) {
    return __int_as_float(__builtin_amdgcn_update_dpp(
        0, __float_as_int(x), 0x130, 0xF, 0xF, true));
}
// lane i <- lane i+1 (int), lane 63 keeps own
__device__ __forceinline__ int dpp_shl1_keep(int x) {
    return __builtin_amdgcn_update_dpp(x, x, 0x130, 0xF, 0xF, false);
}
// exact 2^clamp(d, -126, 127)
__device__ __forceinline__ float exp2i_clamped(int d) {
    int k = 127 + d;
    k = (k < 1) ? 1 : ((k > 254) ? 254 : k);
    return __uint_as_float(((unsigned)k) << 23);
}

struct FwdState {
    float a0, a1, a2;   // alpha (linear, scaled by 2^-esum)
    float s1, k0, k1;   // 2^(eL-e), skm0*s1, skm1*s1
    int   esum;
};
struct BwdState {
    float c0, c1, c2;   // gamma = emit*beta (linear, scaled by 2^-esum)
    float s1b, kA, kB;  // 2^(eR-e), sknA*s1b, sknB*s1b
    int   esum;
};

// 11 VALU per step (proven exact R4-R18)
__device__ __forceinline__ void fwd_step(float em0, float em1, float em2,
                                         FwdState& st, float skm2) {
    float d2 = dpp_shr1_zero(st.a2);
    float d1 = dpp_shr1_zero(st.a1);
    float n0 = fmaf(st.k0, d1, fmaf(st.s1, d2, st.a0)) * em0;
    float n1 = fmaf(st.k1, d2, st.a1 + st.a0) * em1;
    float n2 = fmaf(skm2, st.a0, st.a2 + st.a1) * em2;
    st.a0 = n0; st.a1 = n1; st.a2 = n2;
}
// mirror (proven exact R8-R18)
__device__ __forceinline__ void bwd_step(float em0, float em1, float em2,
                                         BwdState& st, float skm2) {
    float d3 = dpp_shl1_zero(st.c0);
    float d4 = dpp_shl1_zero(st.c1);
    float n0 = fmaf(skm2, st.c2, st.c0 + st.c1) * em0;
    float n1 = fmaf(st.kA, d3, st.c1 + st.c2) * em1;
    float n2 = fmaf(st.kB, d4, fmaf(st.s1b, d3, st.c2)) * em2;
    st.c0 = n0; st.c1 = n1; st.c2 = n2;
}

// Every <=8 steps (proven exact R6-R18)
__device__ __forceinline__ void fwd_rescale(FwdState& st, float skm0, float skm1) {
    float m = fmaxf(fmaxf(st.a0, st.a1), st.a2);
    int ebits = (int)(__float_as_uint(m) >> 23);
    bool dead = (ebits == 0);
    int de = dead ? 0 : (127 - ebits);
    float scz = dead ? 0.0f : exp2i_clamped(de);
    st.a0 *= scz; st.a1 *= scz; st.a2 *= scz;
    st.esum -= de;
    #pragma unroll
    for (int r = 0; r < 5; ++r) {
        int en = dpp_shr1_keep(st.esum);
        st.esum = dead ? en : st.esum;
    }
    int enf = dpp_shr1_keep(st.esum);
    int gap = enf - st.esum;
    int adj = (gap > 64) ? (gap - 64) : 0;
    float sc3 = exp2i_clamped(-adj);
    st.a0 *= sc3; st.a1 *= sc3; st.a2 *= sc3;
    st.esum += adj;
    st.s1 = exp2i_clamped(gap - adj);
    st.k0 = skm0 * st.s1;
    st.k1 = skm1 * st.s1;
}
// R8-hardened bwd rescale (proven exact R8-R18)
__device__ __forceinline__ void bwd_rescale(BwdState& st, float sknA, float sknB) {
    float m = fmaxf(fmaxf(st.c0, st.c1), st.c2);
    int ebits = (int)(__float_as_uint(m) >> 23);
    bool dead = (ebits == 0);
    int de = dead ? 0 : (127 - ebits);
    float scz = dead ? 0.0f : exp2i_clamped(de);
    st.c0 *= scz; st.c1 *= scz; st.c2 *= scz;
    st.esum -= de;
    #pragma unroll
    for (int r = 0; r < 5; ++r) {
        int en = dpp_shl1_keep(st.esum);
        st.esum = dead ? en : st.esum;
    }
    #pragma unroll
    for (int r = 0; r < 3; ++r) {
        int enl = dpp_shr1_keep(st.esum);
        int mn = (enl < st.esum) ? enl : st.esum;
        st.esum = dead ? mn : st.esum;
    }
    int deadR = dpp_shl1_keep(dead ? 1 : 0);
    int enf = dpp_shl1_keep(st.esum);
    int gap = enf - st.esum;
    int adj = (gap > 64) ? (gap - 64) : 0;
    adj = (adj > 126) ? 126 : adj;
    adj = deadR ? 0 : adj;
    float sc3 = exp2i_clamped(-adj);
    st.c0 *= sc3; st.c1 *= sc3; st.c2 *= sc3;
    st.esum += adj;
    float s1b = exp2i_clamped(gap - adj);
    st.s1b = deadR ? 0.f : s1b;
    st.kA = sknA * st.s1b;
    st.kB = sknB * st.s1b;
}

// High-occupancy precompute (R16-proven): prec[p*T + t] = {p1-p0, p0-pb, pb, 0}
__global__ __launch_bounds__(256) void softmax_kernel(
    const float* __restrict__ logits, float4* __restrict__ prec,
    int T, int B, int Ff, int total)
{
    int g = blockIdx.x * 256 + (int)threadIdx.x;
    if (g >= total) return;
    int p = g / T, t = g - p * T;
    int b = p / Ff, f = p - b * Ff;
    int C = 2 * Ff + 1;
    const float* r = logits + ((size_t)t * B + b) * C;
    float xp = r[f], xn = r[Ff + f], xb = r[2 * Ff];
    float m = fmaxf(fmaxf(xp, xn), xb);
    float ep = __expf(xp - m);
    float en = __expf(xn - m);
    float eb = __expf(xb - m);
    float inv = __builtin_amdgcn_rcpf(ep + en + eb);
    float p0 = ep * inv, p1 = en * inv, pb = eb * inv;
    prec[g] = make_float4(p1 - p0, p0 - pb, pb, 0.f);
}

// 8 broadcast ds_read_b128 + the wait in ONE asm statement: consumers are
// data-dependent on post-wait outputs -> no hoisting hazard by construction.
#define LDROWS8(ADDR, R0,R1,R2,R3,R4,R5,R6,R7) \
    asm volatile( \
        "ds_read_b128 %0, %8 offset:0\n\t"  \
        "ds_read_b128 %1, %8 offset:16\n\t" \
        "ds_read_b128 %2, %8 offset:32\n\t" \
        "ds_read_b128 %3, %8 offset:48\n\t" \
        "ds_read_b128 %4, %8 offset:64\n\t" \
        "ds_read_b128 %5, %8 offset:80\n\t" \
        "ds_read_b128 %6, %8 offset:96\n\t" \
        "ds_read_b128 %7, %8 offset:112\n\t" \
        "s_waitcnt lgkmcnt(0)" \
        : "=&v"(R0), "=&v"(R1), "=&v"(R2), "=&v"(R3), \
          "=&v"(R4), "=&v"(R5), "=&v"(R6), "=&v"(R7) \
        : "v"(ADDR));

// Two waves per (b,f): wave 0 = alpha fwd rows 1..m, wave 1 = gamma bwd rows
// TL-2..m+1 (R18 skeleton). Rows are {d, dpb, pb, 0}: row-uniform -> ONE
// broadcast ds_read_b128 per step, batched 8-at-a-time in a single asm with
// its own waitcnt. Emission via R13-proven 5-fma reconstruction.
__global__ __launch_bounds__(128, 1) void ctc_kernel(
    const float4* __restrict__ prec,         // [BF, T] {d, dpb, pb, 0}
    const int* __restrict__ targets,         // [B, F, S]
    const int* __restrict__ input_lengths,   // [B]
    const int* __restrict__ target_lengths,  // [B, F]
    float* __restrict__ loss_out,            // [B*F] (loss / tl)
    int T, int B, int Ff, int S)
{
    const int p = blockIdx.x;
    const int b = p / Ff;
    const int tid = (int)threadIdx.x;
    const int wid = tid >> 6;
    const int lane = tid & 63;
    const int L = 2 * S + 1;

    const int tl = target_lengths[p];
    const int il = input_lengths[b];
    const int tbase = p * S;

    // ---- per-lane static metadata: states l = 3*lane + j (R13 form) ----
    float tf0, tf1, tf2, skm0, skm1, skm2;
    {
        float tf[3], sk[3];
        const int l0 = 3 * lane;
        #pragma unroll
        for (int j = 0; j < 3; ++j) {
            int l = l0 + j;
            float tv = 0.f, sok = 0.f;
            if (l < L && (l & 1)) {
                int s = (l - 1) >> 1;
                int ev = targets[tbase + s];
                tv = (float)ev;
                if (s >= 1) sok = (targets[tbase + s - 1] != ev) ? 1.f : 0.f;
            }
            tf[j] = tv; sk[j] = sok;
        }
        tf0 = tf[0]; tf1 = tf[1]; tf2 = tf[2];
        skm0 = sk[0]; skm1 = sk[1]; skm2 = sk[2];
    }
    const float sknA = dpp_shl1_zero(skm0);   // skip_ok(l0+3)
    const float sknB = dpp_shl1_zero(skm1);   // skip_ok(l0+4)
    const float vP = (float)(lane & 1);       // parity of states l0, l0+2
    const float vQ = 1.0f - vP;               // parity of state l0+1

    // ---- stage rows into LDS: coalesced 16B copies from prec ----
    __shared__ f32x4 slp[640];                // zero-padded past T
    {
        const f32x4* pp = (const f32x4*)(prec + (size_t)p * T);
        #pragma unroll
        for (int j = 0; j < 5; ++j) {         // 5*128 = 640
            int i = tid + (j << 7);
            f32x4 v = {0.f, 0.f, 0.f, 0.f};
            if (i < T) v = pp[i];
            if (i < 640) slp[i] = v;
        }
    }
    __syncthreads();

    const unsigned sbase = (unsigned)(uintptr_t)&slp[0];  // LDS byte offset

    const int TL = (il < T) ? il : T;
    const int m_ = (TL >= 2) ? ((TL - 1) >> 1) : 0;
    const int Fn = m_;                               // fwd steps: rows 1..m_
    const int Bk = (TL >= 2) ? (TL - 2 - m_) : 0;    // bwd steps: rows TL-2..m_+1

    // ---- epilogue shared buffers ----
    __shared__ float sa[192];
    __shared__ float sg[194];
    __shared__ int   seb[65];
    __shared__ float sdot[64];
    __shared__ int   sE[64];

    FwdState fs;
    fs.a0 = 0.f; fs.a1 = 0.f; fs.a2 = 0.f; fs.s1 = 1.f;
    fs.k0 = skm0; fs.k1 = skm1; fs.esum = 0;

#define EMSTEP_F(E) { \
    float iA = fmaf(vP, (E)[1], (E)[2]); \
    float iB = fmaf(vQ, (E)[1], (E)[2]); \
    fwd_step(fmaf(tf0, (E)[0], iA), fmaf(tf1, (E)[0], iB), \
             fmaf(tf2, (E)[0], iA), fs, skm2); }
#define EMSTEP_B(E) { \
    float iA = fmaf(vP, (E)[1], (E)[2]); \
    float iB = fmaf(vQ, (E)[1], (E)[2]); \
    bwd_step(fmaf(tf0, (E)[0], iA), fmaf(tf1, (E)[0], iB), \
             fmaf(tf2, (E)[0], iA), bs, skm2); }

    if (wid == 0) {
        // ================= FORWARD WAVE: rows 1..Fn =================
        {
            f32x4 E0 = slp[0];
            float e1i0 = fmaf(tf1, E0[0], E0[1] + E0[2]);  // em(state1) @ row0
            fs.a0 = (lane == 0) ? E0[2] : 0.f;             // state 0 = blank
            fs.a1 = (lane == 0 && tl > 0) ? e1i0 : 0.f;
            fs.a2 = 0.f;
        }
        const int t_endF = Fn + 1;                   // process t = 1..Fn
        int t = 1;
        f32x4 E0, E1, E2, E3, E4, E5, E6, E7;
        #pragma unroll 1
        for (; t + 8 <= t_endF; t += 8) {
            unsigned addr = sbase + ((unsigned)t << 4);
            LDROWS8(addr, E0, E1, E2, E3, E4, E5, E6, E7)
            fwd_rescale(fs, skm0, skm1);
            EMSTEP_F(E0) EMSTEP_F(E1) EMSTEP_F(E2) EMSTEP_F(E3)
            EMSTEP_F(E4) EMSTEP_F(E5) EMSTEP_F(E6) EMSTEP_F(E7)
        }
        if (t < t_endF) {
            fwd_rescale(fs, skm0, skm1);
            #pragma unroll 1
            for (; t < t_endF; ++t) {
                f32x4 E = slp[t];
                EMSTEP_F(E)
            }
        }
        {
            int l = 3 * lane;
            sa[l] = fs.a0; sa[l + 1] = fs.a1; sa[l + 2] = fs.a2;
        }
    } else {
        // ================= BACKWARD WAVE: rows TL-2 .. m_+1 =================
        BwdState bs;
        {
            f32x4 EL = slp[TL - 1];
            float iA = fmaf(vP, EL[1], EL[2]);
            float iB = fmaf(vQ, EL[1], EL[2]);
            float eL0 = fmaf(tf0, EL[0], iA);
            float eL1 = fmaf(tf1, EL[0], iB);
            float eL2 = fmaf(tf2, EL[0], iA);
            int l0i = 3 * lane;
            int end1 = 2 * tl, end2 = 2 * tl - 1;
            bs.c0 = (l0i == end1 || l0i == end2) ? eL0 : 0.f;
            bs.c1 = (l0i + 1 == end1 || l0i + 1 == end2) ? eL1 : 0.f;
            bs.c2 = (l0i + 2 == end1 || l0i + 2 == end2) ? eL2 : 0.f;
            bs.s1b = 1.f; bs.kA = sknA; bs.kB = sknB;
            bs.esum = 0;
        }
        int k = 0;
        int tr = TL - 2;
        f32x4 E0, E1, E2, E3, E4, E5, E6, E7;
        #pragma unroll 1
        for (; k + 8 <= Bk; k += 8, tr -= 8) {
            unsigned addr = sbase + ((unsigned)(tr - 7) << 4);
            LDROWS8(addr, E0, E1, E2, E3, E4, E5, E6, E7)   // rows tr-7..tr
            bwd_rescale(bs, sknA, sknB);
            EMSTEP_B(E7) EMSTEP_B(E6) EMSTEP_B(E5) EMSTEP_B(E4)
            EMSTEP_B(E3) EMSTEP_B(E2) EMSTEP_B(E1) EMSTEP_B(E0)
        }
        if (k < Bk) {
            bwd_rescale(bs, sknA, sknB);
            #pragma unroll 1
            for (; k < Bk; ++k, --tr) {
                f32x4 E = slp[tr];
                EMSTEP_B(E)
            }
        }
        {
            int l = 3 * lane;
            sg[l] = bs.c0; sg[l + 1] = bs.c1; sg[l + 2] = bs.c2;
            seb[lane] = bs.esum;
            if (lane == 0) { sg[192] = 0.f; sg[193] = 0.f; seb[64] = 0; }
        }
    }
#undef EMSTEP_F
#undef EMSTEP_B
    __syncthreads();

    // ---- midpoint combine (R12 epilogue, proven) ----
    if (wid == 0) {
        int eB = seb[lane];
        float scn = exp2i_clamped(seb[lane + 1] - eB);
        float g0 = sg[3 * lane], g1 = sg[3 * lane + 1], g2 = sg[3 * lane + 2];
        float g3 = sg[3 * lane + 3] * scn;
        float g4 = sg[3 * lane + 4] * scn;
        float s0 = fmaf(skm2, g2, g0 + g1);
        float s1v = fmaf(sknA, g3, g1 + g2);
        float s2v = fmaf(sknB, g4, g2 + g3);
        float dot = fs.a0 * s0 + fs.a1 * s1v + fs.a2 * s2v;
        sdot[lane] = dot;
        sE[lane] = fs.esum + eB;
    }
    __syncthreads();
    if (tid == 0) {
        float loss = 0.f;
        if (TL == 1) {
            float v = sa[2 * tl] + ((tl > 0) ? sa[2 * tl - 1] : 0.f);
            if (v > 0.f) loss = -(__log2f(v) * LN2);
        } else {
            int Emax = -0x40000000;
            for (int i = 0; i < 64; ++i)
                if (sdot[i] > 0.f && sE[i] > Emax) Emax = sE[i];
            if (Emax != -0x40000000) {
                float sum = 0.f;
                for (int i = 0; i < 64; ++i) {
                    int d = sE[i] - Emax;
                    if (d > -127 && sdot[i] > 0.f) sum += sdot[i] * exp2i_clamped(d);
                }
                loss = -((__log2f(sum) + (float)Emax) * LN2);
            }
        }
        float denom = (tl > 0) ? (float)tl : 1.0f;
        loss_out[p] = loss / denom;
    }
}

// Deterministic single-block reduction: out[0] = sum(v) / B
__global__ __launch_bounds__(256) void reduce_kernel(
    const float* __restrict__ v, float* __restrict__ out, int n, float invB)
{
    __shared__ float buf[256];
    float s = 0.f;
    for (int i = (int)threadIdx.x; i < n; i += 256) s += v[i];
    buf[threadIdx.x] = s;
    __syncthreads();
    for (int off = 128; off > 0; off >>= 1) {
        if ((int)threadIdx.x < off) buf[threadIdx.x] += buf[threadIdx.x + off];
        __syncthreads();
    }
    if (threadIdx.x == 0) out[0] = buf[0] * invB;
}

extern "C" void kernel_launch(void* const* d_in, const int* in_sizes, int n_in,
                              void* d_out, int out_size, void* d_ws, size_t ws_size,
                              hipStream_t stream) {
    const float* logits         = (const float*)d_in[0];
    const int*   targets        = (const int*)d_in[1];
    const int*   input_lengths  = (const int*)d_in[2];
    const int*   target_lengths = (const int*)d_in[3];
    float* out = (float*)d_out;

    const int B  = in_sizes[2];            // 32
    const int BF = in_sizes[3];            // B*F = 1120
    const int Ff = BF / B;                 // 35
    const int S  = in_sizes[1] / BF;       // 80
    const int C  = 2 * Ff + 1;             // 71
    const int T  = in_sizes[0] / (B * C);  // 600

    float*  losses = (float*)d_ws;                      // BF floats
    float4* prec   = (float4*)((char*)d_ws + 16384);    // BF*T float4 (~10.75MB)

    int total = BF * T;
    softmax_kernel<<<(total + 255) / 256, 256, 0, stream>>>(
        logits, prec, T, B, Ff, total);
    ctc_kernel<<<BF, 128, 0, stream>>>((const float4*)prec, targets,
                                       input_lengths, target_lengths, losses,
                                       T, B, Ff, S);
    reduce_kernel<<<1, 256, 0, stream>>>(losses, out, BF, 1.0f / (float)B);
}

// Round 20
// 56.392 us; speedup vs baseline: 1.1615x; 1.1615x over previous
//
#include <hip/hip_runtime.h>

#define LN2 0.6931471805599453f

typedef float f32x4 __attribute__((ext_vector_type(4)));

// lane i <- lane i-1 (value), lane 0 <- 0.0f   (wave_shr:1)
__device__ __forceinline__ float dpp_shr1_zero(float x) {
    return __int_as_float(__builtin_amdgcn_update_dpp(
        0, __float_as_int(x), 0x138, 0xF, 0xF, true));
}
// lane i <- lane i-1 (int), lane 0 keeps own
__device__ __forceinline__ int dpp_shr1_keep(int x) {
    return __builtin_amdgcn_update_dpp(x, x, 0x138, 0xF, 0xF, false);
}
// lane i <- lane i+1 (value), lane 63 <- 0.0f  (wave_shl:1)
__device__ __forceinline__ float dpp_shl1_zero(float x) {
    return __int_as_float(__builtin_amdgcn_update_dpp(
        0, __float_as_int(x), 0x130, 0xF, 0xF, true));
}
// lane i <- lane i+1 (int), lane 63 keeps own
__device__ __forceinline__ int dpp_shl1_keep(int x) {
    return __builtin_amdgcn_update_dpp(x, x, 0x130, 0xF, 0xF, false);
}
// exact 2^clamp(d, -126, 127)
__device__ __forceinline__ float exp2i_clamped(int d) {
    int k = 127 + d;
    k = (k < 1) ? 1 : ((k > 254) ? 254 : k);
    return __uint_as_float(((unsigned)k) << 23);
}
__device__ __forceinline__ float sel3(int e, float v0, float v1, float v2) {
    return (e == 2) ? v2 : ((e == 1) ? v1 : v0);
}

struct FwdState {
    float a0, a1, a2;   // alpha (linear, scaled by 2^-esum)
    float s1, k0, k1;   // 2^(eL-e), skm0*s1, skm1*s1
    int   esum;
};
struct BwdState {
    float c0, c1, c2;   // gamma = emit*beta (linear, scaled by 2^-esum)
    float s1b, kA, kB;  // 2^(eR-e), sknA*s1b, sknB*s1b
    int   esum;
};

// 11 VALU per step (proven exact R4-R19)
__device__ __forceinline__ void fwd_step(float em0, float em1, float em2,
                                         FwdState& st, float skm2) {
    float d2 = dpp_shr1_zero(st.a2);
    float d1 = dpp_shr1_zero(st.a1);
    float n0 = fmaf(st.k0, d1, fmaf(st.s1, d2, st.a0)) * em0;
    float n1 = fmaf(st.k1, d2, st.a1 + st.a0) * em1;
    float n2 = fmaf(skm2, st.a0, st.a2 + st.a1) * em2;
    st.a0 = n0; st.a1 = n1; st.a2 = n2;
}
// mirror (proven exact R8-R19)
__device__ __forceinline__ void bwd_step(float em0, float em1, float em2,
                                         BwdState& st, float skm2) {
    float d3 = dpp_shl1_zero(st.c0);
    float d4 = dpp_shl1_zero(st.c1);
    float n0 = fmaf(skm2, st.c2, st.c0 + st.c1) * em0;
    float n1 = fmaf(st.kA, d3, st.c1 + st.c2) * em1;
    float n2 = fmaf(st.kB, d4, fmaf(st.s1b, d3, st.c2)) * em2;
    st.c0 = n0; st.c1 = n1; st.c2 = n2;
}

// Every 8 steps (proven exact R6-R19)
__device__ __forceinline__ void fwd_rescale(FwdState& st, float skm0, float skm1) {
    float m = fmaxf(fmaxf(st.a0, st.a1), st.a2);
    int ebits = (int)(__float_as_uint(m) >> 23);
    bool dead = (ebits == 0);
    int de = dead ? 0 : (127 - ebits);
    float scz = dead ? 0.0f : exp2i_clamped(de);
    st.a0 *= scz; st.a1 *= scz; st.a2 *= scz;
    st.esum -= de;
    #pragma unroll
    for (int r = 0; r < 5; ++r) {
        int en = dpp_shr1_keep(st.esum);
        st.esum = dead ? en : st.esum;
    }
    int enf = dpp_shr1_keep(st.esum);
    int gap = enf - st.esum;
    int adj = (gap > 64) ? (gap - 64) : 0;
    float sc3 = exp2i_clamped(-adj);
    st.a0 *= sc3; st.a1 *= sc3; st.a2 *= sc3;
    st.esum += adj;
    st.s1 = exp2i_clamped(gap - adj);
    st.k0 = skm0 * st.s1;
    st.k1 = skm1 * st.s1;
}
// R8-hardened bwd rescale (proven exact R8-R19)
__device__ __forceinline__ void bwd_rescale(BwdState& st, float sknA, float sknB) {
    float m = fmaxf(fmaxf(st.c0, st.c1), st.c2);
    int ebits = (int)(__float_as_uint(m) >> 23);
    bool dead = (ebits == 0);
    int de = dead ? 0 : (127 - ebits);
    float scz = dead ? 0.0f : exp2i_clamped(de);
    st.c0 *= scz; st.c1 *= scz; st.c2 *= scz;
    st.esum -= de;
    #pragma unroll
    for (int r = 0; r < 5; ++r) {
        int en = dpp_shl1_keep(st.esum);
        st.esum = dead ? en : st.esum;
    }
    #pragma unroll
    for (int r = 0; r < 3; ++r) {
        int enl = dpp_shr1_keep(st.esum);
        int mn = (enl < st.esum) ? enl : st.esum;
        st.esum = dead ? mn : st.esum;
    }
    int deadR = dpp_shl1_keep(dead ? 1 : 0);
    int enf = dpp_shl1_keep(st.esum);
    int gap = enf - st.esum;
    int adj = (gap > 64) ? (gap - 64) : 0;
    adj = (adj > 126) ? 126 : adj;
    adj = deadR ? 0 : adj;
    float sc3 = exp2i_clamped(-adj);
    st.c0 *= sc3; st.c1 *= sc3; st.c2 *= sc3;
    st.esum += adj;
    float s1b = exp2i_clamped(gap - adj);
    st.s1b = deadR ? 0.f : s1b;
    st.kA = sknA * st.s1b;
    st.kB = sknB * st.s1b;
}

// Precompute with COALESCED reads: consecutive threads sweep p for fixed t,
// so logits[(t*B+b)*C + f] reads are contiguous runs (f fastest; blank column
// broadcasts). Writes prec[p*T + t] are scattered 16B -> absorbed by L2.
__global__ __launch_bounds__(256) void softmax_kernel(
    const float* __restrict__ logits, float4* __restrict__ prec,
    int T, int B, int Ff, int BF, int total)
{
    int g = blockIdx.x * 256 + (int)threadIdx.x;
    if (g >= total) return;
    int t = g / BF, p = g - t * BF;
    int b = p / Ff, f = p - b * Ff;
    int C = 2 * Ff + 1;
    const float* r = logits + ((size_t)t * B + b) * C;
    float xp = r[f], xn = r[Ff + f], xb = r[2 * Ff];
    float m = fmaxf(fmaxf(xp, xn), xb);
    float ep = __expf(xp - m);
    float en = __expf(xn - m);
    float eb = __expf(xb - m);
    float inv = __builtin_amdgcn_rcpf(ep + en + eb);
    prec[(size_t)p * T + t] = make_float4(ep * inv, en * inv, eb * inv, 0.f);
}

// Two waves per (b,f): wave 0 = alpha fwd rows 1..m, wave 1 = gamma bwd rows
// TL-2..m+1 (R18 verbatim — fastest observed hot loop, 343 cy/step).
__global__ __launch_bounds__(128, 1) void ctc_kernel(
    const float4* __restrict__ prec,         // [BF, T] {p_pos, p_neg, p_blank, 0}
    const int* __restrict__ targets,         // [B, F, S]
    const int* __restrict__ input_lengths,   // [B]
    const int* __restrict__ target_lengths,  // [B, F]
    float* __restrict__ loss_out,            // [B*F] (loss / tl)
    int T, int B, int Ff, int S)
{
    const int p = blockIdx.x;
    const int b = p / Ff;
    const int tid = (int)threadIdx.x;
    const int wid = tid >> 6;
    const int lane = tid & 63;
    const int L = 2 * S + 1;

    const int tl = target_lengths[p];
    const int il = input_lengths[b];
    const int tbase = p * S;

    // ---- per-lane static metadata: states l = 3*lane + j ----
    int e0i, e1i, e2i;
    float skm0, skm1, skm2;
    {
        int e[3]; float sk[3];
        const int l0 = 3 * lane;
        #pragma unroll
        for (int j = 0; j < 3; ++j) {
            int l = l0 + j;
            int ev = 2; float sok = 0.f;
            if (l < L && (l & 1)) {
                int s = (l - 1) >> 1;
                ev = targets[tbase + s];
                if (s >= 1) sok = (targets[tbase + s - 1] != ev) ? 1.f : 0.f;
            }
            e[j] = ev; sk[j] = sok;
        }
        e0i = e[0]; e1i = e[1]; e2i = e[2];
        skm0 = sk[0]; skm1 = sk[1]; skm2 = sk[2];
    }
    const float sknA = dpp_shl1_zero(skm0);   // skip_ok(l0+3)
    const float sknB = dpp_shl1_zero(skm1);   // skip_ok(l0+4)

    // ---- stage rows into LDS: coalesced 16B copies from prec ----
    __shared__ f32x4 slp[640];                // zero-padded past T
    {
        const f32x4* pp = (const f32x4*)(prec + (size_t)p * T);
        #pragma unroll
        for (int j = 0; j < 5; ++j) {         // 5*128 = 640
            int i = tid + (j << 7);
            f32x4 v = {0.f, 0.f, 0.f, 0.f};
            if (i < T) v = pp[i];
            if (i < 640) slp[i] = v;
        }
    }
    __syncthreads();

    // per-lane emission base pointers (byte offset e*4 within each 16B row)
    const char* base8 = (const char*)slp;
    const char* qt0 = base8 + (e0i << 2);
    const char* qt1 = base8 + (e1i << 2);
    const char* qt2 = base8 + (e2i << 2);

    const int TL = (il < T) ? il : T;
    const int m_ = (TL >= 2) ? ((TL - 1) >> 1) : 0;
    const int Fn = m_;                               // fwd steps: rows 1..m_
    const int Bk = (TL >= 2) ? (TL - 2 - m_) : 0;    // bwd steps: rows TL-2..m_+1

    // ---- epilogue shared buffers ----
    __shared__ float sa[192];
    __shared__ float sg[194];
    __shared__ int   seb[65];
    __shared__ float sdot[64];
    __shared__ int   sE[64];

    FwdState fs;
    fs.a0 = 0.f; fs.a1 = 0.f; fs.a2 = 0.f; fs.s1 = 1.f;
    fs.k0 = skm0; fs.k1 = skm1; fs.esum = 0;

    if (wid == 0) {
        // ================= FORWARD WAVE (R12 loop, verbatim) =================
        {
            f32x4 E0 = slp[0];
            fs.a0 = (lane == 0) ? E0[2] : 0.f;
            fs.a1 = (lane == 0 && tl > 0) ? sel3(e1i, E0[0], E0[1], E0[2]) : 0.f;
            fs.a2 = 0.f;
        }
        const int t_endF = Fn + 1;                   // process t = 1..Fn
        const char* pr0 = qt0 + 16;
        const char* pr1 = qt1 + 16;
        const char* pr2 = qt2 + 16;
#define LDE(OFF, E) { E[0] = *(const float*)(pr0 + (OFF)); \
                      E[1] = *(const float*)(pr1 + (OFF)); \
                      E[2] = *(const float*)(pr2 + (OFF)); }
        float A0[3], A1[3], A2[3], A3[3], B0[3], B1[3], B2[3], B3[3];
        float C0[3], C1[3], C2[3], C3[3], D0[3], D1[3], D2[3], D3[3];
        int t = 1;
        if (t + 15 < t_endF) {
            LDE(  0, A0); LDE( 16, A1); LDE( 32, A2); LDE( 48, A3);
            LDE( 64, B0); LDE( 80, B1); LDE( 96, B2); LDE(112, B3);
            LDE(128, C0); LDE(144, C1); LDE(160, C2); LDE(176, C3);
            LDE(192, D0); LDE(208, D1); LDE(224, D2); LDE(240, D3);
        }
        #pragma unroll 1
        for (; t + 15 < t_endF; t += 16) {
            fwd_rescale(fs, skm0, skm1);
            fwd_step(A0[0], A0[1], A0[2], fs, skm2);
            fwd_step(A1[0], A1[1], A1[2], fs, skm2);
            fwd_step(A2[0], A2[1], A2[2], fs, skm2);
            fwd_step(A3[0], A3[1], A3[2], fs, skm2);
            LDE(256, A0); LDE(272, A1); LDE(288, A2); LDE(304, A3);
            fwd_step(B0[0], B0[1], B0[2], fs, skm2);
            fwd_step(B1[0], B1[1], B1[2], fs, skm2);
            fwd_step(B2[0], B2[1], B2[2], fs, skm2);
            fwd_step(B3[0], B3[1], B3[2], fs, skm2);
            LDE(320, B0); LDE(336, B1); LDE(352, B2); LDE(368, B3);
            fwd_rescale(fs, skm0, skm1);
            fwd_step(C0[0], C0[1], C0[2], fs, skm2);
            fwd_step(C1[0], C1[1], C1[2], fs, skm2);
            fwd_step(C2[0], C2[1], C2[2], fs, skm2);
            fwd_step(C3[0], C3[1], C3[2], fs, skm2);
            LDE(384, C0); LDE(400, C1); LDE(416, C2); LDE(432, C3);
            fwd_step(D0[0], D0[1], D0[2], fs, skm2);
            fwd_step(D1[0], D1[1], D1[2], fs, skm2);
            fwd_step(D2[0], D2[1], D2[2], fs, skm2);
            fwd_step(D3[0], D3[1], D3[2], fs, skm2);
            LDE(448, D0); LDE(464, D1); LDE(480, D2); LDE(496, D3);
            pr0 += 256; pr1 += 256; pr2 += 256;
        }
#undef LDE
        #pragma unroll 1
        for (; t < t_endF; ++t) {
            int o = t << 4;
            float e0 = *(const float*)(qt0 + o);
            float e1 = *(const float*)(qt1 + o);
            float e2 = *(const float*)(qt2 + o);
            fwd_step(e0, e1, e2, fs, skm2);
        }
        {
            int l = 3 * lane;
            sa[l] = fs.a0; sa[l + 1] = fs.a1; sa[l + 2] = fs.a2;
        }
    } else {
        // ================= BACKWARD WAVE (R12 loop, verbatim) =================
        BwdState bs;
        {
            int oTL = (TL - 1) << 4;
            float eL0 = *(const float*)(qt0 + oTL);
            float eL1 = *(const float*)(qt1 + oTL);
            float eL2 = *(const float*)(qt2 + oTL);
            int l0i = 3 * lane;
            int end1 = 2 * tl, end2 = 2 * tl - 1;
            bs.c0 = (l0i == end1 || l0i == end2) ? eL0 : 0.f;
            bs.c1 = (l0i + 1 == end1 || l0i + 1 == end2) ? eL1 : 0.f;
            bs.c2 = (l0i + 2 == end1 || l0i + 2 == end2) ? eL2 : 0.f;
            bs.s1b = 1.f; bs.kA = sknA; bs.kB = sknB;
            bs.esum = 0;
        }
        const char* pb0 = qt0 + ((TL - 2) << 4);
        const char* pb1 = qt1 + ((TL - 2) << 4);
        const char* pb2 = qt2 + ((TL - 2) << 4);
#define LDB(OFF, E) { E[0] = *(const float*)(pb0 - (OFF)); \
                      E[1] = *(const float*)(pb1 - (OFF)); \
                      E[2] = *(const float*)(pb2 - (OFF)); }
        float GA0[3], GA1[3], GA2[3], GA3[3], GB0[3], GB1[3], GB2[3], GB3[3];
        float GC0[3], GC1[3], GC2[3], GC3[3], GD0[3], GD1[3], GD2[3], GD3[3];
        int k = 0;
        if (k + 15 < Bk) {
            LDB(  0, GA0); LDB( 16, GA1); LDB( 32, GA2); LDB( 48, GA3);
            LDB( 64, GB0); LDB( 80, GB1); LDB( 96, GB2); LDB(112, GB3);
            LDB(128, GC0); LDB(144, GC1); LDB(160, GC2); LDB(176, GC3);
            LDB(192, GD0); LDB(208, GD1); LDB(224, GD2); LDB(240, GD3);
        }
        #pragma unroll 1
        for (; k + 15 < Bk; k += 16) {
            bwd_rescale(bs, sknA, sknB);
            bwd_step(GA0[0], GA0[1], GA0[2], bs, skm2);
            bwd_step(GA1[0], GA1[1], GA1[2], bs, skm2);
            bwd_step(GA2[0], GA2[1], GA2[2], bs, skm2);
            bwd_step(GA3[0], GA3[1], GA3[2], bs, skm2);
            LDB(256, GA0); LDB(272, GA1); LDB(288, GA2); LDB(304, GA3);
            bwd_step(GB0[0], GB0[1], GB0[2], bs, skm2);
            bwd_step(GB1[0], GB1[1], GB1[2], bs, skm2);
            bwd_step(GB2[0], GB2[1], GB2[2], bs, skm2);
            bwd_step(GB3[0], GB3[1], GB3[2], bs, skm2);
            LDB(320, GB0); LDB(336, GB1); LDB(352, GB2); LDB(368, GB3);
            bwd_rescale(bs, sknA, sknB);
            bwd_step(GC0[0], GC0[1], GC0[2], bs, skm2);
            bwd_step(GC1[0], GC1[1], GC1[2], bs, skm2);
            bwd_step(GC2[0], GC2[1], GC2[2], bs, skm2);
            bwd_step(GC3[0], GC3[1], GC3[2], bs, skm2);
            LDB(384, GC0); LDB(400, GC1); LDB(416, GC2); LDB(432, GC3);
            bwd_step(GD0[0], GD0[1], GD0[2], bs, skm2);
            bwd_step(GD1[0], GD1[1], GD1[2], bs, skm2);
            bwd_step(GD2[0], GD2[1], GD2[2], bs, skm2);
            bwd_step(GD3[0], GD3[1], GD3[2], bs, skm2);
            LDB(448, GD0); LDB(464, GD1); LDB(480, GD2); LDB(496, GD3);
            pb0 -= 256; pb1 -= 256; pb2 -= 256;
        }
#undef LDB
        int trow = TL - 2 - k;
        #pragma unroll 1
        for (; trow >= m_ + 1; --trow) {
            int o = trow << 4;
            float g0 = *(const float*)(qt0 + o);
            float g1 = *(const float*)(qt1 + o);
            float g2 = *(const float*)(qt2 + o);
            bwd_step(g0, g1, g2, bs, skm2);
        }
        {
            int l = 3 * lane;
            sg[l] = bs.c0; sg[l + 1] = bs.c1; sg[l + 2] = bs.c2;
            seb[lane] = bs.esum;
            if (lane == 0) { sg[192] = 0.f; sg[193] = 0.f; seb[64] = 0; }
        }
    }
    __syncthreads();

    // ---- midpoint combine (R12 epilogue, proven) ----
    if (wid == 0) {
        int eB = seb[lane];
        float scn = exp2i_clamped(seb[lane + 1] - eB);
        float g0 = sg[3 * lane], g1 = sg[3 * lane + 1], g2 = sg[3 * lane + 2];
        float g3 = sg[3 * lane + 3] * scn;
        float g4 = sg[3 * lane + 4] * scn;
        float s0 = fmaf(skm2, g2, g0 + g1);
        float s1v = fmaf(sknA, g3, g1 + g2);
        float s2v = fmaf(sknB, g4, g2 + g3);
        float dot = fs.a0 * s0 + fs.a1 * s1v + fs.a2 * s2v;
        sdot[lane] = dot;
        sE[lane] = fs.esum + eB;
    }
    __syncthreads();
    if (tid == 0) {
        float loss = 0.f;
        if (TL == 1) {
            float v = sa[2 * tl] + ((tl > 0) ? sa[2 * tl - 1] : 0.f);
            if (v > 0.f) loss = -(__log2f(v) * LN2);
        } else {
            int Emax = -0x40000000;
            for (int i = 0; i < 64; ++i)
                if (sdot[i] > 0.f && sE[i] > Emax) Emax = sE[i];
            if (Emax != -0x40000000) {
                float sum = 0.f;
                for (int i = 0; i < 64; ++i) {
                    int d = sE[i] - Emax;
                    if (d > -127 && sdot[i] > 0.f) sum += sdot[i] * exp2i_clamped(d);
                }
                loss = -((__log2f(sum) + (float)Emax) * LN2);
            }
        }
        float denom = (tl > 0) ? (float)tl : 1.0f;
        loss_out[p] = loss / denom;
    }
}

// Deterministic single-block reduction: out[0] = sum(v) / B
__global__ __launch_bounds__(256) void reduce_kernel(
    const float* __restrict__ v, float* __restrict__ out, int n, float invB)
{
    __shared__ float buf[256];
    float s = 0.f;
    for (int i = (int)threadIdx.x; i < n; i += 256) s += v[i];
    buf[threadIdx.x] = s;
    __syncthreads();
    for (int off = 128; off > 0; off >>= 1) {
        if ((int)threadIdx.x < off) buf[threadIdx.x] += buf[threadIdx.x + off];
        __syncthreads();
    }
    if (threadIdx.x == 0) out[0] = buf[0] * invB;
}

extern "C" void kernel_launch(void* const* d_in, const int* in_sizes, int n_in,
                              void* d_out, int out_size, void* d_ws, size_t ws_size,
                              hipStream_t stream) {
    const float* logits         = (const float*)d_in[0];
    const int*   targets        = (const int*)d_in[1];
    const int*   input_lengths  = (const int*)d_in[2];
    const int*   target_lengths = (const int*)d_in[3];
    float* out = (float*)d_out;

    const int B  = in_sizes[2];            // 32
    const int BF = in_sizes[3];            // B*F = 1120
    const int Ff = BF / B;                 // 35
    const int S  = in_sizes[1] / BF;       // 80
    const int C  = 2 * Ff + 1;             // 71
    const int T  = in_sizes[0] / (B * C);  // 600

    float*  losses = (float*)d_ws;                      // BF floats
    float4* prec   = (float4*)((char*)d_ws + 16384);    // BF*T float4 (~10.75MB)

    int total = BF * T;
    softmax_kernel<<<(total + 255) / 256, 256, 0, stream>>>(
        logits, prec, T, B, Ff, BF, total);
    ctc_kernel<<<BF, 128, 0, stream>>>((const float4*)prec, targets,
                                       input_lengths, target_lengths, losses,
                                       T, B, Ff, S);
    reduce_kernel<<<1, 256, 0, stream>>>(losses, out, BF, 1.0f / (float)B);
}